// Round 15
// baseline (474.098 us; speedup 1.0000x reference)
//
#include <hip/hip_runtime.h>

#define H 128
#define TDEPTH 10
#define NPT 1023
#define NTREES 512

typedef unsigned short bf16_t;
typedef unsigned int u32;
typedef __attribute__((ext_vector_type(8))) short bf16x8;
typedef __attribute__((ext_vector_type(4))) float f32x4;

__device__ __forceinline__ float rcp_(float x) { return __builtin_amdgcn_rcpf(x); }
__device__ __forceinline__ float sig_(float x) { return rcp_(1.0f + __expf(-x)); }
__device__ __forceinline__ float th_(float x)  { return 1.0f - 2.0f * rcp_(__expf(2.0f * x) + 1.0f); }
__device__ __forceinline__ float b2f(u32 u) {
    union { float f; u32 u; } v; v.u = u << 16; return v.f;
}
// float from the HIGH 16 bits of a packed h|c word (c plane)
__device__ __forceinline__ float b2f_hi(u32 u) {
    union { float f; u32 u; } v; v.u = u & 0xffff0000u; return v.f;
}
__device__ __forceinline__ u32 f2b(float f) {
    union { float f; u32 u; } v; v.f = f;
    return (v.u + 0x7fffu + ((v.u >> 16) & 1u)) >> 16;   // RNE
}
// one-instruction pack: lo16 = bf16(h), hi16 = bf16(c)  (RNE)
__device__ __forceinline__ u32 pk_hc(float h, float c) {
    u32 w;
    asm("v_cvt_pk_bf16_f32 %0, %1, %2" : "=v"(w) : "v"(h), "v"(c));
    return w;
}
__device__ __forceinline__ bf16x8 ld8(const bf16_t* p) {
    return *reinterpret_cast<const bf16x8*>(p);
}
__device__ __forceinline__ bf16x8 ld8c(const char* p) {
    return *reinterpret_cast<const bf16x8*>(p);
}
// XOR-swizzled LDS byte offset for [row][128 bf16] tiles (row stride 256 B).
__device__ __forceinline__ int swz(int row, int colbytes) {
    return row * 256 + (colbytes ^ ((row & 7) << 4));
}
#define MFMA(a,b,c) __builtin_amdgcn_mfma_f32_16x16x32_bf16(a,b,c,0,0,0)

// LDS regions (64-node tile): x, h0, h1 = 3 x 16 KB = 48 KB dynamic
#define R_X  0
#define R_H0 16384
#define R_H1 32768
#define LDSSZ 49152

// ---------------------------------------------------------------------------
// Weight pack. 0..131071: plane-interleaved Wb[(feat*8+p)*128+k],
// p: 0 Wi | 1 Wo | 2 Wu | 3 Ui | 4 Uo | 5 Uu | 6 Wf | 7 Uf.
// 131072..133119: W_out padded to 16 rows x 128 (rows 5-15 zero).
// ---------------------------------------------------------------------------
__global__ void pack_weights(const float* __restrict__ W_iou, const float* __restrict__ U_iou,
                             const float* __restrict__ W_f,   const float* __restrict__ U_f,
                             const float* __restrict__ W_out, bf16_t* __restrict__ Wb)
{
    int i = blockIdx.x * 256 + threadIdx.x;
    if (i < 131072) {
        int k    = i & 127;
        int p    = (i >> 7) & 7;
        int feat = i >> 10;
        float v;
        switch (p) {
            case 0: v = W_iou[(      feat) * H + k]; break;
            case 1: v = W_iou[(128 + feat) * H + k]; break;
            case 2: v = W_iou[(256 + feat) * H + k]; break;
            case 3: v = U_iou[(      feat) * H + k]; break;
            case 4: v = U_iou[(128 + feat) * H + k]; break;
            case 5: v = U_iou[(256 + feat) * H + k]; break;
            case 6: v = W_f  [feat * H + k]; break;
            default: v = U_f [feat * H + k]; break;
        }
        Wb[i] = (bf16_t)f2b(v);
    } else {
        int j = i - 131072;
        int cls = j >> 7, k = j & 127;
        Wb[i] = (bf16_t)f2b(cls < 5 ? W_out[cls * H + k] : 0.0f);
    }
}

__global__ void pack_E(const float* __restrict__ E, bf16_t* __restrict__ Eb)
{
    int i = blockIdx.x * 256 + threadIdx.x;
    Eb[i] = (bf16_t)f2b(E[i]);
}

// ---------------------------------------------------------------------------
// Leaf (l=9): 64 nodes/block, 512 threads; x staged once per block (swizzled).
// ---------------------------------------------------------------------------
__global__ __launch_bounds__(512, 4) void leaf_mfma(
    const int* __restrict__ wordid, const bf16_t* __restrict__ Eb,
    const bf16_t* __restrict__ Wb,
    const float* __restrict__ b_iou, const float* __restrict__ b_Uiou,
    u32* __restrict__ hc_cur, int t0)
{
    const int level = TDEPTH - 1;
    __shared__ __align__(16) char x_s[64 * 256];   // 16 KB, swizzled

    const int tid = threadIdx.x;
    const int n0  = blockIdx.x * 64;

    for (int idx = tid; idx < 1024; idx += 512) {
        int q = idx & 15, m = idx >> 4;
        int g = n0 + m;
        int t = g >> level, i = g & ((1 << level) - 1);
        int wid = wordid[(t0 + t) * NPT + (1 << level) - 1 + i];
        *(uint4*)(x_s + swz(m, q * 16)) = *(const uint4*)(Eb + (size_t)wid * H + q * 8);
    }
    __syncthreads();

    const int lane = tid & 63;
    const int w    = tid >> 6;
    const int l15  = lane & 15;
    const int kg   = lane >> 4;
    const int feat = w * 16 + l15;
    const bf16_t* wbase = Wb + (size_t)feat * 1024 + kg * 8;

    f32x4 z = {0.f, 0.f, 0.f, 0.f};
    f32x4 acc[3][4];
#pragma unroll
    for (int g = 0; g < 3; ++g)
#pragma unroll
        for (int m = 0; m < 4; ++m) acc[g][m] = z;

#pragma unroll
    for (int ks = 0; ks < 4; ++ks) {
        bf16x8 W0 = ld8(wbase + ks * 32 + 0 * 128);
        bf16x8 W1 = ld8(wbase + ks * 32 + 1 * 128);
        bf16x8 W2 = ld8(wbase + ks * 32 + 2 * 128);
        const int cb = (ks * 32 + kg * 8) * 2;
#pragma unroll
        for (int mt = 0; mt < 4; ++mt) {
            bf16x8 xa = ld8c(x_s + swz(mt * 16 + l15, cb));
            acc[0][mt] = MFMA(xa, W0, acc[0][mt]);
            acc[1][mt] = MFMA(xa, W1, acc[1][mt]);
            acc[2][mt] = MFMA(xa, W2, acc[2][mt]);
        }
    }

    float bi = b_iou[      feat] + b_Uiou[      feat];
    float bo = b_iou[128 + feat] + b_Uiou[128 + feat];
    float bu = b_iou[256 + feat] + b_Uiou[256 + feat];
#pragma unroll
    for (int mt = 0; mt < 4; ++mt) {
#pragma unroll
        for (int r = 0; r < 4; ++r) {
            int g = n0 + mt * 16 + kg * 4 + r;
            float iv = sig_(acc[0][mt][r] + bi);
            float ov = sig_(acc[1][mt][r] + bo);
            float uv = th_ (acc[2][mt][r] + bu);
            float cl = iv * uv;
            float hl = ov * th_(cl);
            hc_cur[(size_t)g * H + feat] = pk_hc(hl, cl);
        }
    }
}

// ---------------------------------------------------------------------------
// Internal level l: 64 nodes/block, 512 threads, 48 KB dynamic LDS (x,h0,h1).
// Child c values fetched directly from global in the epilogue (coalesced,
// L2-warm from the staging read). Single barrier.
// ---------------------------------------------------------------------------
__global__ __launch_bounds__(512, 3) void internal_mfma(
    const int* __restrict__ wordid, const bf16_t* __restrict__ Eb,
    const bf16_t* __restrict__ Wb,
    const float* __restrict__ b_iou, const float* __restrict__ b_Uiou,
    const float* __restrict__ b_Wf,  const float* __restrict__ b_Uf,
    const u32* __restrict__ hc_prev, u32* __restrict__ hc_cur,
    const float* __restrict__ b_out, float* __restrict__ out,
    int level, int t0, int M)
{
    extern __shared__ __align__(16) char lds_raw[];
    char* x_s  = lds_raw + R_X;
    char* h0_s = lds_raw + R_H0;
    char* h1_s = lds_raw + R_H1;

    const int tid = threadIdx.x;
    const int n0  = blockIdx.x * 64;
    const int nlim = M - n0;           // valid nodes in this block (usually 64)
    const int lane = tid & 63;
    const int w    = tid >> 6;
    const int l15  = lane & 15;
    const int kg   = lane >> 4;
    const int feat = w * 16 + l15;

    // stage children h: 128 rows x 32 uint4 (8/thread); extract h-halves only
    for (int idx = tid; idx < 4096; idx += 512) {
        int q = idx & 31, j = idx >> 5;
        uint4 v = *(const uint4*)(hc_prev + (size_t)(2 * n0 + j) * H + q * 4);
        u32 hlo = (v.x & 0xffffu) | (v.y << 16);
        u32 hhi = (v.z & 0xffffu) | (v.w << 16);
        int row = j >> 1;
        char* hd = ((j & 1) ? h1_s : h0_s) + swz(row, q * 8);
        ((u32*)hd)[0] = hlo; ((u32*)hd)[1] = hhi;
    }
    // stage x: 64 rows x 16 uint4 (2/thread)
    for (int idx = tid; idx < 1024; idx += 512) {
        int q = idx & 15, m = idx >> 4;
        int mm = (m < nlim) ? m : 0;
        int g = n0 + mm;
        int t = g >> level, i = g & ((1 << level) - 1);
        int wid = wordid[(t0 + t) * NPT + (1 << level) - 1 + i];
        *(uint4*)(x_s + swz(m, q * 16)) = *(const uint4*)(Eb + (size_t)wid * H + q * 8);
    }
    __syncthreads();

    const bf16_t* wbase = Wb + (size_t)feat * 1024 + kg * 8;
    f32x4 z = {0.f, 0.f, 0.f, 0.f};
    f32x4 acc[6][4];
#pragma unroll
    for (int g = 0; g < 6; ++g)
#pragma unroll
        for (int m = 0; m < 4; ++m) acc[g][m] = z;

#pragma unroll
    for (int ks = 0; ks < 4; ++ks) {
        bf16x8 W0 = ld8(wbase + ks * 32 + 0 * 128);
        bf16x8 W1 = ld8(wbase + ks * 32 + 1 * 128);
        bf16x8 W2 = ld8(wbase + ks * 32 + 2 * 128);
        bf16x8 W3 = ld8(wbase + ks * 32 + 3 * 128);
        bf16x8 W4 = ld8(wbase + ks * 32 + 4 * 128);
        bf16x8 W5 = ld8(wbase + ks * 32 + 5 * 128);
        bf16x8 W6 = ld8(wbase + ks * 32 + 6 * 128);
        bf16x8 W7 = ld8(wbase + ks * 32 + 7 * 128);
        const int cb = (ks * 32 + kg * 8) * 2;
#pragma unroll
        for (int mt = 0; mt < 4; ++mt) {
            const int row = mt * 16 + l15;
            bf16x8 xa  = ld8c(x_s  + swz(row, cb));
            bf16x8 h0a = ld8c(h0_s + swz(row, cb));
            bf16x8 h1a = ld8c(h1_s + swz(row, cb));
            acc[0][mt] = MFMA(h1a, W3, MFMA(h0a, W3, MFMA(xa, W0, acc[0][mt])));
            acc[1][mt] = MFMA(h1a, W4, MFMA(h0a, W4, MFMA(xa, W1, acc[1][mt])));
            acc[2][mt] = MFMA(h1a, W5, MFMA(h0a, W5, MFMA(xa, W2, acc[2][mt])));
            acc[3][mt] = MFMA(xa,  W6, acc[3][mt]);
            acc[4][mt] = MFMA(h0a, W7, acc[4][mt]);
            acc[5][mt] = MFMA(h1a, W7, acc[5][mt]);
        }
    }

    // issue child-c loads (coalesced 64B lines, L2-warm); latency hidden by
    // the logits MFMA section below
    u32 c0w[4][4], c1w[4][4];
#pragma unroll
    for (int mt = 0; mt < 4; ++mt)
#pragma unroll
        for (int r = 0; r < 4; ++r) {
            int nb = mt * 16 + kg * 4 + r;
            int gc = n0 + ((nb < nlim) ? nb : 0);
            c0w[mt][r] = hc_prev[(size_t)(2 * gc)     * H + feat];
            c1w[mt][r] = hc_prev[(size_t)(2 * gc + 1) * H + feat];
        }

    // child (level+1) logits via MFMA: 8 waves x 16 children.
    {
        const int pr = w & 1;
        const int rowbase = (w >> 1) * 16;
        const char* hbuf = pr ? h1_s : h0_s;
        const bf16_t* Wob = Wb + 131072;
        f32x4 lacc = z;
#pragma unroll
        for (int ks = 0; ks < 4; ++ks) {
            bf16x8 ha = ld8c(hbuf + swz(rowbase + l15, (ks * 32 + kg * 8) * 2));
            bf16x8 wo = ld8(Wob + (size_t)l15 * 128 + ks * 32 + kg * 8);
            lacc = MFMA(ha, wo, lacc);
        }
        if (l15 < 5) {
            float bo5 = b_out[l15];
            int lc = level + 1;
#pragma unroll
            for (int r = 0; r < 4; ++r) {
                int m = rowbase + kg * 4 + r;       // parent index in block
                if (m < nlim) {
                    int gc = 2 * (n0 + m) + pr;
                    int tt = gc >> lc, ii = gc & ((1 << lc) - 1);
                    out[(size_t)((t0 + tt) * NPT + (1 << lc) - 1 + ii) * 5 + l15] = lacc[r] + bo5;
                }
            }
        }
    }

    float bi  = b_iou[      feat] + b_Uiou[      feat];
    float bo  = b_iou[128 + feat] + b_Uiou[128 + feat];
    float bu  = b_iou[256 + feat] + b_Uiou[256 + feat];
    float bfv = b_Wf[feat] + b_Uf[feat];
#pragma unroll
    for (int mt = 0; mt < 4; ++mt) {
#pragma unroll
        for (int r = 0; r < 4; ++r) {
            int nb = mt * 16 + kg * 4 + r;
            if (nb < nlim) {
                int g = n0 + nb;
                float iv = sig_(acc[0][mt][r] + bi);
                float ov = sig_(acc[1][mt][r] + bo);
                float uv = th_ (acc[2][mt][r] + bu);
                float fx = acc[3][mt][r];
                float f0 = sig_(fx + acc[4][mt][r] + bfv);
                float f1 = sig_(fx + acc[5][mt][r] + bfv);
                float c0 = b2f_hi(c0w[mt][r]);
                float c1 = b2f_hi(c1w[mt][r]);
                float cl = iv * uv + f0 * c0 + f1 * c1;
                float hl = ov * th_(cl);
                hc_cur[(size_t)g * H + feat] = pk_hc(hl, cl);
            }
        }
    }
}

// ---------------------------------------------------------------------------
// Root logits (level 0): one wave per tree, h from interleaved hc
// ---------------------------------------------------------------------------
__global__ void logits_root(
    const u32* __restrict__ hc, const float* __restrict__ W_out,
    const float* __restrict__ b_out, float* __restrict__ out,
    int M, int t0)
{
    int wv     = (blockIdx.x * blockDim.x + threadIdx.x) >> 6;
    int lane   = threadIdx.x & 63;
    int nwaves = (gridDim.x * blockDim.x) >> 6;
    for (int g = wv; g < M; g += nwaves) {
        float h0 = b2f(hc[(size_t)g * H + lane] & 0xffffu);
        float h1 = b2f(hc[(size_t)g * H + 64 + lane] & 0xffffu);
#pragma unroll
        for (int c = 0; c < 5; ++c) {
            float p = h0 * W_out[c * H + lane] + h1 * W_out[c * H + 64 + lane];
#pragma unroll
            for (int off = 32; off >= 1; off >>= 1) p += __shfl_xor(p, off, 64);
            if (lane == 0) out[(size_t)(t0 + g) * NPT * 5 + c] = p + b_out[c];
        }
    }
}

// ---------------------------------------------------------------------------
extern "C" void kernel_launch(void* const* d_in, const int* in_sizes, int n_in,
                              void* d_out, int out_size, void* d_ws, size_t ws_size,
                              hipStream_t stream)
{
    (void)in_sizes; (void)n_in; (void)out_size;
    const int*   wordid = (const int*)  d_in[0];
    const float* E      = (const float*)d_in[1];
    const float* W_iou  = (const float*)d_in[2];
    const float* b_iou  = (const float*)d_in[3];
    const float* U_iou  = (const float*)d_in[4];
    const float* b_Uiou = (const float*)d_in[5];
    const float* W_f    = (const float*)d_in[6];
    const float* b_Wf   = (const float*)d_in[7];
    const float* U_f    = (const float*)d_in[8];
    const float* b_Uf   = (const float*)d_in[9];
    const float* W_out  = (const float*)d_in[10];
    const float* b_out  = (const float*)d_in[11];
    float* out = (float*)d_out;

    // ws: Wb (260 KB) | Eb (8 MB) | hcA (odd levels) | hcB (even levels)
    bf16_t* Wb = (bf16_t*)d_ws;
    bf16_t* Eb = Wb + 133120;
    char* dyn  = (char*)(Eb + (size_t)32000 * H);
    const size_t fixed_bytes = (133120 + (size_t)32000 * H) * 2;

    // per-tree dynamic bytes: hcA 512 rows*512B + hcB 256 rows*512B = 393216
    int C = 1;
    while (C < 16 && fixed_bytes + (size_t)(NTREES / C) * 393216u > ws_size) C <<= 1;
    const int T = NTREES / C;

    u32* hcA = (u32*)dyn;
    u32* hcB = hcA + (size_t)T * 512 * H;

    pack_weights<<<520, 256, 0, stream>>>(W_iou, U_iou, W_f, U_f, W_out, Wb);
    pack_E<<<16000, 256, 0, stream>>>(E, Eb);

    for (int chunk = 0; chunk < C; ++chunk) {
        int t0 = chunk * T;
        for (int l = TDEPTH - 1; l >= 0; --l) {
            int M = T << l;
            u32* hc_cur  = (l & 1) ? hcA : hcB;
            u32* hc_prev = (l & 1) ? hcB : hcA;

            if (l == TDEPTH - 1) {
                leaf_mfma<<<M / 64, 512, 0, stream>>>(
                    wordid, Eb, Wb, b_iou, b_Uiou, hc_cur, t0);
            } else {
                int blocks = (M + 63) / 64;
                internal_mfma<<<blocks, 512, LDSSZ, stream>>>(
                    wordid, Eb, Wb, b_iou, b_Uiou, b_Wf, b_Uf,
                    hc_prev, hc_cur, b_out, out, l, t0, M);
            }
        }
        int blocksR = (T / 4 < 4096) ? ((T + 3) / 4) : 4096;
        if (blocksR < 1) blocksR = 1;
        logits_root<<<blocksR, 256, 0, stream>>>(hcB, W_out, b_out, out, T, t0);
    }
}

// Round 16
// 388.060 us; speedup vs baseline: 1.2217x; 1.2217x over previous
//
#include <hip/hip_runtime.h>

#define H 128
#define TDEPTH 10
#define NPT 1023
#define NTREES 512

typedef unsigned short bf16_t;
typedef unsigned int u32;
typedef __attribute__((ext_vector_type(8))) short bf16x8;
typedef __attribute__((ext_vector_type(4))) float f32x4;

__device__ __forceinline__ float rcp_(float x) { return __builtin_amdgcn_rcpf(x); }
__device__ __forceinline__ float sig_(float x) { return rcp_(1.0f + __expf(-x)); }
__device__ __forceinline__ float th_(float x)  { return 1.0f - 2.0f * rcp_(__expf(2.0f * x) + 1.0f); }
__device__ __forceinline__ float b2f(u32 u) {
    union { float f; u32 u; } v; v.u = u << 16; return v.f;
}
__device__ __forceinline__ bf16_t f2b16(float f) {
    union { float f; u32 u; } v; v.f = f;
    return (bf16_t)((v.u + 0x7fffu + ((v.u >> 16) & 1u)) >> 16);   // RNE
}
__device__ __forceinline__ bf16x8 ld8(const bf16_t* p) {
    return *reinterpret_cast<const bf16x8*>(p);
}
__device__ __forceinline__ bf16x8 ld8c(const char* p) {
    return *reinterpret_cast<const bf16x8*>(p);
}
// async HBM->LDS, 16B per lane (dest = lds base + lane*16)
__device__ __forceinline__ void gload16(const void* g, void* l) {
    __builtin_amdgcn_global_load_lds(
        (const __attribute__((address_space(1))) void*)g,
        (__attribute__((address_space(3))) void*)l, 16, 0, 0);
}
#define MFMA(a,b,c) __builtin_amdgcn_mfma_f32_16x16x32_bf16(a,b,c,0,0,0)

// per-tile buffer: x 8KB | h 16KB | c 16KB  = 40KB; two buffers
#define R_H  8192
#define R_C  24576
#define BUFSZ 40960

// ---------------------------------------------------------------------------
__global__ void pack_weights(const float* __restrict__ W_iou, const float* __restrict__ U_iou,
                             const float* __restrict__ W_f,   const float* __restrict__ U_f,
                             const float* __restrict__ W_out, bf16_t* __restrict__ Wb)
{
    int i = blockIdx.x * 256 + threadIdx.x;
    if (i < 131072) {
        int k    = i & 127;
        int p    = (i >> 7) & 7;
        int feat = i >> 10;
        float v;
        switch (p) {
            case 0: v = W_iou[(      feat) * H + k]; break;
            case 1: v = W_iou[(128 + feat) * H + k]; break;
            case 2: v = W_iou[(256 + feat) * H + k]; break;
            case 3: v = U_iou[(      feat) * H + k]; break;
            case 4: v = U_iou[(128 + feat) * H + k]; break;
            case 5: v = U_iou[(256 + feat) * H + k]; break;
            case 6: v = W_f  [feat * H + k]; break;
            default: v = U_f [feat * H + k]; break;
        }
        Wb[i] = f2b16(v);
    } else {
        int j = i - 131072;
        int cls = j >> 7, k = j & 127;
        Wb[i] = f2b16(cls < 5 ? W_out[cls * H + k] : 0.0f);
    }
}

__global__ void pack_E(const float* __restrict__ E, bf16_t* __restrict__ Eb)
{
    int i = blockIdx.x * 256 + threadIdx.x;
    Eb[i] = f2b16(E[i]);
}

// ---------------------------------------------------------------------------
// Leaf (l=9): 64 nodes/block, 512 threads (R13 structure, separate h/c out).
// ---------------------------------------------------------------------------
__global__ __launch_bounds__(512, 4) void leaf_mfma(
    const int* __restrict__ wordid, const bf16_t* __restrict__ Eb,
    const bf16_t* __restrict__ Wb,
    const float* __restrict__ b_iou, const float* __restrict__ b_Uiou,
    bf16_t* __restrict__ h_cur, bf16_t* __restrict__ c_cur, int t0)
{
    const int level = TDEPTH - 1;
    __shared__ __align__(16) char x_s[64 * 256];

    const int tid = threadIdx.x;
    const int n0  = blockIdx.x * 64;

    for (int idx = tid; idx < 1024; idx += 512) {
        int q = idx & 15, m = idx >> 4;
        int g = n0 + m;
        int t = g >> level, i = g & ((1 << level) - 1);
        int wid = wordid[(t0 + t) * NPT + (1 << level) - 1 + i];
        *(uint4*)(x_s + m * 256 + ((q * 16) ^ ((m & 7) << 4))) =
            *(const uint4*)(Eb + (size_t)wid * H + q * 8);
    }
    __syncthreads();

    const int lane = tid & 63;
    const int w    = tid >> 6;
    const int l15  = lane & 15;
    const int kg   = lane >> 4;
    const int feat = w * 16 + l15;
    const bf16_t* wbase = Wb + (size_t)feat * 1024 + kg * 8;

    f32x4 z = {0.f, 0.f, 0.f, 0.f};
    f32x4 acc[3][4];
#pragma unroll
    for (int g = 0; g < 3; ++g)
#pragma unroll
        for (int m = 0; m < 4; ++m) acc[g][m] = z;

#pragma unroll
    for (int ks = 0; ks < 4; ++ks) {
        bf16x8 W0 = ld8(wbase + ks * 32 + 0 * 128);
        bf16x8 W1 = ld8(wbase + ks * 32 + 1 * 128);
        bf16x8 W2 = ld8(wbase + ks * 32 + 2 * 128);
        const int cb = (ks * 32 + kg * 8) * 2;
#pragma unroll
        for (int mt = 0; mt < 4; ++mt) {
            int row = mt * 16 + l15;
            bf16x8 xa = ld8c(x_s + row * 256 + (cb ^ ((row & 7) << 4)));
            acc[0][mt] = MFMA(xa, W0, acc[0][mt]);
            acc[1][mt] = MFMA(xa, W1, acc[1][mt]);
            acc[2][mt] = MFMA(xa, W2, acc[2][mt]);
        }
    }

    float bi = b_iou[      feat] + b_Uiou[      feat];
    float bo = b_iou[128 + feat] + b_Uiou[128 + feat];
    float bu = b_iou[256 + feat] + b_Uiou[256 + feat];
#pragma unroll
    for (int mt = 0; mt < 4; ++mt) {
#pragma unroll
        for (int r = 0; r < 4; ++r) {
            int g = n0 + mt * 16 + kg * 4 + r;
            float iv = sig_(acc[0][mt][r] + bi);
            float ov = sig_(acc[1][mt][r] + bo);
            float uv = th_ (acc[2][mt][r] + bu);
            float cl = iv * uv;
            float hl = ov * th_(cl);
            h_cur[(size_t)g * H + feat] = f2b16(hl);
            c_cur[(size_t)g * H + feat] = f2b16(cl);
        }
    }
}

// ---------------------------------------------------------------------------
// Internal level: 32-node tiles, nt tiles/block, double-buffered LDS filled by
// async global_load_lds (source pre-swizzled). Prefetch of tile t+1 issued
// after tile t's VMEM reads; lands during epilogue+barrier.
// ---------------------------------------------------------------------------
__global__ __launch_bounds__(512, 2) void internal_mfma(
    const int* __restrict__ wordid, const bf16_t* __restrict__ Eb,
    const bf16_t* __restrict__ Wb,
    const float* __restrict__ b_iou, const float* __restrict__ b_Uiou,
    const float* __restrict__ b_Wf,  const float* __restrict__ b_Uf,
    const bf16_t* __restrict__ h_prev, const bf16_t* __restrict__ c_prev,
    bf16_t* __restrict__ h_cur, bf16_t* __restrict__ c_cur,
    const float* __restrict__ b_out, float* __restrict__ out,
    int level, int t0, int nt)
{
    extern __shared__ __align__(16) char lds_raw[];   // 2 * BUFSZ

    const int tid  = threadIdx.x;
    const int lane = tid & 63;
    const int w    = tid >> 6;
    const int l15  = lane & 15;
    const int kg   = lane >> 4;
    const int feat = w * 16 + l15;
    const int tilebase = blockIdx.x * nt;

    const float bi  = b_iou[      feat] + b_Uiou[      feat];
    const float bo  = b_iou[128 + feat] + b_Uiou[128 + feat];
    const float bu  = b_iou[256 + feat] + b_Uiou[256 + feat];
    const float bfv = b_Wf[feat] + b_Uf[feat];
    const bf16_t* wbase = Wb + (size_t)feat * 1024 + kg * 8;
    const f32x4 z = {0.f, 0.f, 0.f, 0.f};

    const int lrow = lane >> 4;            // 0..3 (row within 1KB chunk)
    const int colb = (lane & 15) * 16;

    // issue 40 async chunk-loads (5 per wave) for tile t into buf
    auto issue = [&](int t, char* buf) {
        int n0 = (tilebase + t) * 32;
#pragma unroll
        for (int cc = 0; cc < 5; ++cc) {
            int ch = w + cc * 8;
            const char* src;
            if (ch < 8) {                       // x plane, rows 0..31
                int row = ch * 4 + lrow;
                int g = n0 + row;
                int tt = g >> level, ii = g & ((1 << level) - 1);
                int wid = wordid[(t0 + tt) * NPT + (1 << level) - 1 + ii];
                src = (const char*)Eb + (size_t)wid * 256 + (colb ^ ((row & 7) << 4));
            } else if (ch < 24) {               // h plane, child rows 0..63
                int row = (ch - 8) * 4 + lrow;
                src = (const char*)h_prev + ((size_t)(2 * n0) + row) * 256
                    + (colb ^ (((row >> 1) & 7) << 4));
            } else {                            // c plane, child rows 0..63
                int row = (ch - 24) * 4 + lrow;
                src = (const char*)c_prev + ((size_t)(2 * n0) + row) * 256
                    + (colb ^ ((row & 7) << 4));
            }
            gload16(src, buf + ch * 1024);
        }
    };

    issue(0, lds_raw);
    __syncthreads();

    for (int t = 0; t < nt; ++t) {
        char* buf = lds_raw + (t & 1) * BUFSZ;
        char* x_s = buf;
        char* h_s = buf + R_H;
        char* c_s = buf + R_C;
        const int n0 = (tilebase + t) * 32;

        f32x4 acc[6][2];
#pragma unroll
        for (int g = 0; g < 6; ++g)
#pragma unroll
            for (int m = 0; m < 2; ++m) acc[g][m] = z;

#pragma unroll
        for (int ks = 0; ks < 4; ++ks) {
            bf16x8 W0 = ld8(wbase + ks * 32 + 0 * 128);
            bf16x8 W1 = ld8(wbase + ks * 32 + 1 * 128);
            bf16x8 W2 = ld8(wbase + ks * 32 + 2 * 128);
            bf16x8 W3 = ld8(wbase + ks * 32 + 3 * 128);
            bf16x8 W4 = ld8(wbase + ks * 32 + 4 * 128);
            bf16x8 W5 = ld8(wbase + ks * 32 + 5 * 128);
            bf16x8 W6 = ld8(wbase + ks * 32 + 6 * 128);
            bf16x8 W7 = ld8(wbase + ks * 32 + 7 * 128);
            const int cb = (ks * 32 + kg * 8) * 2;
#pragma unroll
            for (int mt = 0; mt < 2; ++mt) {
                const int row = mt * 16 + l15;
                const int sw  = (row & 7) << 4;
                bf16x8 xa  = ld8c(x_s + row * 256 + (cb ^ sw));
                bf16x8 h0a = ld8c(h_s + (2 * row)     * 256 + (cb ^ sw));
                bf16x8 h1a = ld8c(h_s + (2 * row + 1) * 256 + (cb ^ sw));
                acc[0][mt] = MFMA(h1a, W3, MFMA(h0a, W3, MFMA(xa, W0, acc[0][mt])));
                acc[1][mt] = MFMA(h1a, W4, MFMA(h0a, W4, MFMA(xa, W1, acc[1][mt])));
                acc[2][mt] = MFMA(h1a, W5, MFMA(h0a, W5, MFMA(xa, W2, acc[2][mt])));
                acc[3][mt] = MFMA(xa,  W6, acc[3][mt]);
                acc[4][mt] = MFMA(h0a, W7, acc[4][mt]);
                acc[5][mt] = MFMA(h1a, W7, acc[5][mt]);
            }
        }

        // child (level+1) logits via MFMA: waves 0-3, 16 children each
        if (w < 4) {
            const int pr = (w & 2) ? 1 : 0;
            const int mbase = (w & 1) * 16;
            const bf16_t* Wob = Wb + 131072;
            f32x4 lacc = z;
#pragma unroll
            for (int ks = 0; ks < 4; ++ks) {
                const int cb = (ks * 32 + kg * 8) * 2;
                int prow = mbase + l15;
                bf16x8 ha = ld8c(h_s + (size_t)(2 * prow + pr) * 256
                                 + (cb ^ ((prow & 7) << 4)));
                bf16x8 wo = ld8(Wob + (size_t)l15 * 128 + ks * 32 + kg * 8);
                lacc = MFMA(ha, wo, lacc);
            }
            if (l15 < 5) {
                float bo5 = b_out[l15];
                int lc = level + 1;
#pragma unroll
                for (int r = 0; r < 4; ++r) {
                    int m  = mbase + kg * 4 + r;
                    int gc = 2 * (n0 + m) + pr;
                    int tt = gc >> lc, ii = gc & ((1 << lc) - 1);
                    out[(size_t)((t0 + tt) * NPT + (1 << lc) - 1 + ii) * 5 + l15] = lacc[r] + bo5;
                }
            }
        }

        // prefetch next tile (after all VMEM reads of this tile)
        if (t + 1 < nt) issue(t + 1, lds_raw + ((t + 1) & 1) * BUFSZ);

        // epilogue: c from LDS, gates, stores
#pragma unroll
        for (int mt = 0; mt < 2; ++mt) {
#pragma unroll
            for (int r = 0; r < 4; ++r) {
                int nb = mt * 16 + kg * 4 + r;
                int g  = n0 + nb;
                float iv = sig_(acc[0][mt][r] + bi);
                float ov = sig_(acc[1][mt][r] + bo);
                float uv = th_ (acc[2][mt][r] + bu);
                float fx = acc[3][mt][r];
                float f0 = sig_(fx + acc[4][mt][r] + bfv);
                float f1 = sig_(fx + acc[5][mt][r] + bfv);
                float c0 = b2f((u32)*(const bf16_t*)(c_s + (2 * nb) * 256
                              + ((feat * 2) ^ (((2 * nb) & 7) << 4))));
                float c1 = b2f((u32)*(const bf16_t*)(c_s + (2 * nb + 1) * 256
                              + ((feat * 2) ^ (((2 * nb + 1) & 7) << 4))));
                float cl = iv * uv + f0 * c0 + f1 * c1;
                float hl = ov * th_(cl);
                h_cur[(size_t)g * H + feat] = f2b16(hl);
                c_cur[(size_t)g * H + feat] = f2b16(cl);
            }
        }

        __syncthreads();   // drains prefetch (landed during epilogue) + fences LDS
    }
}

// ---------------------------------------------------------------------------
__global__ void logits_root(
    const bf16_t* __restrict__ h0buf, const float* __restrict__ W_out,
    const float* __restrict__ b_out, float* __restrict__ out,
    int M, int t0)
{
    int wv     = (blockIdx.x * blockDim.x + threadIdx.x) >> 6;
    int lane   = threadIdx.x & 63;
    int nwaves = (gridDim.x * blockDim.x) >> 6;
    for (int g = wv; g < M; g += nwaves) {
        float h0 = b2f((u32)h0buf[(size_t)g * H + lane]);
        float h1 = b2f((u32)h0buf[(size_t)g * H + 64 + lane]);
#pragma unroll
        for (int c = 0; c < 5; ++c) {
            float p = h0 * W_out[c * H + lane] + h1 * W_out[c * H + 64 + lane];
#pragma unroll
            for (int off = 32; off >= 1; off >>= 1) p += __shfl_xor(p, off, 64);
            if (lane == 0) out[(size_t)(t0 + g) * NPT * 5 + c] = p + b_out[c];
        }
    }
}

// ---------------------------------------------------------------------------
extern "C" void kernel_launch(void* const* d_in, const int* in_sizes, int n_in,
                              void* d_out, int out_size, void* d_ws, size_t ws_size,
                              hipStream_t stream)
{
    (void)in_sizes; (void)n_in; (void)out_size;
    const int*   wordid = (const int*)  d_in[0];
    const float* E      = (const float*)d_in[1];
    const float* W_iou  = (const float*)d_in[2];
    const float* b_iou  = (const float*)d_in[3];
    const float* U_iou  = (const float*)d_in[4];
    const float* b_Uiou = (const float*)d_in[5];
    const float* W_f    = (const float*)d_in[6];
    const float* b_Wf   = (const float*)d_in[7];
    const float* U_f    = (const float*)d_in[8];
    const float* b_Uf   = (const float*)d_in[9];
    const float* W_out  = (const float*)d_in[10];
    const float* b_out  = (const float*)d_in[11];
    float* out = (float*)d_out;

    // ws: Wb (260 KB) | Eb (8 MB) | hA cA (odd levels) | hB cB (even levels)
    bf16_t* Wb = (bf16_t*)d_ws;
    bf16_t* Eb = Wb + 133120;
    bf16_t* dyn = Eb + (size_t)32000 * H;
    const size_t fixed_bytes = (133120 + (size_t)32000 * H) * 2;

    // per-tree bytes: (512+512+256+256) rows * 256 B = 393216
    int C = 1;
    while (C < 16 && fixed_bytes + (size_t)(NTREES / C) * 393216u > ws_size) C <<= 1;
    const int T = NTREES / C;

    bf16_t* hA = dyn;
    bf16_t* cA = hA + (size_t)T * 512 * H;
    bf16_t* hB = cA + (size_t)T * 512 * H;
    bf16_t* cB = hB + (size_t)T * 256 * H;

    pack_weights<<<520, 256, 0, stream>>>(W_iou, U_iou, W_f, U_f, W_out, Wb);
    pack_E<<<16000, 256, 0, stream>>>(E, Eb);

    for (int chunk = 0; chunk < C; ++chunk) {
        int t0 = chunk * T;
        for (int l = TDEPTH - 1; l >= 0; --l) {
            int M = T << l;
            bf16_t* h_cur  = (l & 1) ? hA : hB;
            bf16_t* c_cur  = (l & 1) ? cA : cB;
            bf16_t* h_prev = (l & 1) ? hB : hA;
            bf16_t* c_prev = (l & 1) ? cB : cA;

            if (l == TDEPTH - 1) {
                leaf_mfma<<<M / 64, 512, 0, stream>>>(
                    wordid, Eb, Wb, b_iou, b_Uiou, h_cur, c_cur, t0);
            } else {
                int tiles  = M / 32;
                int blocks = tiles < 512 ? tiles : 512;
                int nt     = tiles / blocks;
                internal_mfma<<<blocks, 512, 2 * BUFSZ, stream>>>(
                    wordid, Eb, Wb, b_iou, b_Uiou, b_Wf, b_Uf,
                    h_prev, c_prev, h_cur, c_cur, b_out, out, l, t0, nt);
            }
        }
        int blocksR = (T / 4 < 4096) ? ((T + 3) / 4) : 4096;
        if (blocksR < 1) blocksR = 1;
        logits_root<<<blocksR, 256, 0, stream>>>(hB, W_out, b_out, out, T, t0);
    }
}